// Round 11
// baseline (224.299 us; speedup 1.0000x reference)
//
#include <hip/hip_runtime.h>
#include <math.h>

// SoftMSM loss on MI355X — round 10.
// Single-wave skewed pipeline (R8 skeleton, verified absmax 0.0) with:
//   1. sched_barrier(0) between weight phase and chain phase — R9 proved the
//      scheduler re-interleaves (VGPR stuck at 32) putting exp latency on the
//      serial chain; this pins the 16 exps ahead of the 32-FMA chain.
//   2. v2f (ext_vector_type(2)) packed math over the row pair -> v_pk_*_f32.
//   3. R7's float2 LDS layout (3x ds_read_b64, ~0 conflicts) instead of R8's
//      float4 (32B stride, 302k conflict cycles).
//
// Recursion (c=1, gamma=1), F = e^{i+j} * exp(-cost):
//   F[i,j] = F[i-1,j-1]*A + F[i-1,j]*B + F[i,j-1]*C
//   A = e^{2-m2}; B = (dx*(x-y)>0 ? ex2+Em : 1); C = (dy*(x-y)<0 ? edy2+Em : 1)
//   cost = 1022 - log(F[511,511])
// Lane j owns cols [8j, 8j+8); step t processes row-pair p = t - j (rows
// 2p, 2p+1). Boundary via DPP wave_shr:1 (VALU pipe). Carries dc0/dc1/dc2 =
// lastcol(2p-1, 2p, 2p+1); per-lane scale 2^kacc rebased to max(kacc, k_in)
// (shifts <= 0, overflow-proof); per-step normalize into [0.5, 1).

#define TT 512
#define BATCH 64
#define G 8                      // cols per lane
#define NP (TT / 2)              // 256 row-pairs
#define STEPS (NP + 63)          // 319

#define C1F 1.2011224087864498f  // sqrt(log2 e)
#define C2F 2.8853900817779268f  // 2*log2 e
#define K2F 0.13533528323661270f // e^-2
#define LN2F 0.69314718055994531f

#if __has_builtin(__builtin_amdgcn_exp2f)
#define EXP2F(x) __builtin_amdgcn_exp2f(x)
#else
#define EXP2F(x) __expf((x) * LN2F)
#endif

typedef float v2f __attribute__((ext_vector_type(2)));

// lane i gets lane i-1's src; lane 0 gets `old`  (wave_shr:1 = 0x138)
__device__ __forceinline__ float dpp_shr1_f(float src, float old) {
  return __int_as_float(__builtin_amdgcn_update_dpp(
      __float_as_int(old), __float_as_int(src), 0x138, 0xF, 0xF, false));
}
__device__ __forceinline__ int dpp_shr1_i(int src, int old) {
  return __builtin_amdgcn_update_dpp(old, src, 0x138, 0xF, 0xF, false);
}

__global__ __launch_bounds__(64, 1) void msm_kernel(const float* __restrict__ x,
                                                    const float* __restrict__ y,
                                                    float* __restrict__ ws) {
  const int b = blockIdx.x;
  const int j = threadIdx.x;         // 0..63

  __shared__ float2 XC2[NP];         // {xc(2p), xc(2p+1)}, xc = x * C1
  __shared__ float2 DX2[NP];         // {dx(2p), dx(2p+1)}
  __shared__ float2 EX2[NP];         // {exp(-dx^2) pair}

  // ---- setup: x-derived row data (lane j covers rows 8j..8j+7 = pairs 4j..4j+3)
  {
    const float4* xv = (const float4*)(x + b * TT);
    float4 a0 = xv[j * 2], a1 = xv[j * 2 + 1];
    float rx[G] = {a0.x, a0.y, a0.z, a0.w, a1.x, a1.y, a1.z, a1.w};
    float prev = (j > 0) ? x[b * TT + 8 * j - 1] : 0.0f;
    float cc[G], dd[G], ee[G];
#pragma unroll
    for (int k = 0; k < G; ++k) {
      float dx = rx[k] - prev;       // row 0's dx unused (up input is 0)
      prev = rx[k];
      cc[k] = rx[k] * C1F;
      dd[k] = dx;
      ee[k] = __expf(-dx * dx);
    }
#pragma unroll
    for (int q = 0; q < 4; ++q) {
      XC2[4 * j + q] = make_float2(cc[2 * q], cc[2 * q + 1]);
      DX2[4 * j + q] = make_float2(dd[2 * q], dd[2 * q + 1]);
      EX2[4 * j + q] = make_float2(ee[2 * q], ee[2 * q + 1]);
    }
  }
  // ---- setup: y-derived column registers ----
  float yc[G], dyS[G], edy2[G];
  {
    const float4* yv = (const float4*)(y + b * TT);
    float4 a0 = yv[j * 2], a1 = yv[j * 2 + 1];
    float ry[G] = {a0.x, a0.y, a0.z, a0.w, a1.x, a1.y, a1.z, a1.w};
    float prev = (j > 0) ? y[b * TT + 8 * j - 1] : 0.0f;
#pragma unroll
    for (int k = 0; k < G; ++k) {
      float dy = ry[k] - prev;       // col 0's dy unused (left input is 0)
      prev = ry[k];
      yc[k] = ry[k] * C1F;
      dyS[k] = dy;
      edy2[k] = __expf(-dy * dy);
    }
  }
  __syncthreads();

  float Ep[G];                       // F[2p-1, owned cols], lane scale 2^kacc
#pragma unroll
  for (int k = 0; k < G; ++k) Ep[k] = 0.0f;
  float dc0 = 0.0f, dc1 = 0.0f, dc2 = 0.0f;  // lastcol(2p-1, 2p, 2p+1)
  int kacc = 0;

  // prefetch row-pair for t=0 (valid for lane 0; others clamped/masked)
  float2 nxc = XC2[0], ndx = DX2[0], nex = EX2[0];

  for (int t = 0; t < STEPS; ++t) {
    // boundary exchange via DPP (VALU pipe, no LDS)
    float r0 = dpp_shr1_f(dc0, 0.0f);
    float r1 = dpp_shr1_f(dc1, 0.0f);
    float r2 = dpp_shr1_f(dc2, 0.0f);
    int k_in = dpp_shr1_i(kacc, kacc);       // lane 0 keeps own kacc
    if (t == 0 && j == 0) r0 = K2F;          // global seed F[-1,-1] = e^{-2}

    const int p = t - j;
    // rotate prefetched row data; issue next prefetch early (covers a full step)
    const float2 cxc = nxc, cdx = ndx, cex = nex;
    {
      int pn = t + 1 - j;
      pn = (pn < 0) ? 0 : ((pn > NP - 1) ? NP - 1 : pn);
      nxc = XC2[pn]; ndx = DX2[pn]; nex = EX2[pn];
    }

    if (p >= 0 && p < NP) {
      if (p == 0) kacc = k_in;               // pipeline entry: adopt scale
      const int knew = (k_in > kacc) ? k_in : kacc;
      const float mMe = ldexpf(1.0f, kacc - knew);  // <= 1
      const float mIn = ldexpf(1.0f, k_in - knew);  // <= 1
      kacc = knew;
      const float dv0 = r0 * mIn, dv1 = r1 * mIn, dv2 = r2 * mIn;
      const float nd0 = dc2 * mMe;           // lastcol(2p-1) for next send
      float u[G];
#pragma unroll
      for (int k = 0; k < G; ++k) u[k] = Ep[k] * mMe;

      // ---- phase 1: ALL weights, packed over the row pair ----
      const v2f xcp = {cxc.x, cxc.y};
      const v2f dxp = {cdx.x, cdx.y};
      const v2f exp_ = {cex.x, cex.y};
      v2f A2[G], B2[G], C2[G];
#pragma unroll
      for (int k = 0; k < G; ++k) {
        v2f s1 = xcp - yc[k];                // v_pk_add (splat)
        v2f arg = C2F - s1 * s1;             // v_pk_fma
        v2f A;
        A.x = EXP2F(arg.x);
        A.y = EXP2F(arg.y);
        v2f Em = A * K2F;
        v2f Bs = exp_ + Em;
        v2f Cs = edy2[k] + Em;
        v2f gu = dxp * s1;
        v2f gl = dyS[k] * s1;
        A2[k] = A;
        B2[k].x = (gu.x > 0.0f) ? Bs.x : 1.0f;
        B2[k].y = (gu.y > 0.0f) ? Bs.y : 1.0f;
        C2[k].x = (gl.x < 0.0f) ? Cs.x : 1.0f;
        C2[k].y = (gl.y < 0.0f) ? Cs.y : 1.0f;
      }
      // pin: weights fully scheduled before the chain (R9: compiler sank them)
      __builtin_amdgcn_sched_barrier(0);

      // ---- phase 2: pure-FMA chains ----
      float pa[G], T0[G];
      pa[0] = __fmaf_rn(dv0, A2[0].x, u[0] * B2[0].x);
#pragma unroll
      for (int k = 1; k < G; ++k)
        pa[k] = __fmaf_rn(u[k - 1], A2[k].x, u[k] * B2[k].x);
      T0[0] = __fmaf_rn(dv1, C2[0].x, pa[0]);
#pragma unroll
      for (int k = 1; k < G; ++k)
        T0[k] = __fmaf_rn(T0[k - 1], C2[k].x, pa[k]);

      float pb[G], T1[G];
      pb[0] = __fmaf_rn(dv1, A2[0].y, T0[0] * B2[0].y);
#pragma unroll
      for (int k = 1; k < G; ++k)
        pb[k] = __fmaf_rn(T0[k - 1], A2[k].y, T0[k] * B2[k].y);
      T1[0] = __fmaf_rn(dv2, C2[0].y, pb[0]);
#pragma unroll
      for (int k = 1; k < G; ++k)
        T1[k] = __fmaf_rn(T1[k - 1], C2[k].y, pb[k]);

      dc0 = nd0;
      dc1 = T0[G - 1];
      // normalize carried state into [0.5, 1)
      float vmax = fmaxf(fmaxf(fmaxf(T1[0], T1[1]), fmaxf(T1[2], T1[3])),
                         fmaxf(fmaxf(T1[4], T1[5]), fmaxf(T1[6], T1[7])));
      vmax = fmaxf(vmax, fmaxf(dc0, dc1));
      unsigned ue = (__float_as_uint(vmax) >> 23) & 0xFFu;
      int e = (int)ue - 126;
      float sc = ldexpf(1.0f, -e);
#pragma unroll
      for (int k = 0; k < G; ++k) Ep[k] = T1[k] * sc;
      dc0 *= sc;
      dc1 *= sc;
      dc2 = Ep[G - 1];
      kacc += e;
    }
  }

  if (j == 63) {
    // cost = 1022 - log(F_true)
    ws[b] = 1022.0f - (__logf(Ep[G - 1]) + (float)kacc * LN2F);
  }
}

__global__ __launch_bounds__(64) void reduce_kernel(const float* __restrict__ ws,
                                                    float* __restrict__ out) {
  float v = ws[threadIdx.x];
#pragma unroll
  for (int off = 32; off > 0; off >>= 1) v += __shfl_down(v, off);
  if (threadIdx.x == 0) out[0] = v * (1.0f / BATCH);
}

extern "C" void kernel_launch(void* const* d_in, const int* in_sizes, int n_in,
                              void* d_out, int out_size, void* d_ws, size_t ws_size,
                              hipStream_t stream) {
  const float* x = (const float*)d_in[0];
  const float* y = (const float*)d_in[1];
  float* ws = (float*)d_ws;
  float* out = (float*)d_out;
  msm_kernel<<<BATCH, 64, 0, stream>>>(x, y, ws);
  reduce_kernel<<<1, 64, 0, stream>>>(ws, out);
}